// Round 1
// baseline (646.357 us; speedup 1.0000x reference)
//
#include <hip/hip_runtime.h>
#include <math.h>

typedef __bf16 bf16_t;
typedef __attribute__((ext_vector_type(8))) __bf16 bf16x8;
typedef __attribute__((ext_vector_type(4))) float f32x4;

#define AS_G __attribute__((address_space(1)))
#define AS_L __attribute__((address_space(3)))

__device__ __forceinline__ f32x4 mfma16(bf16x8 a, bf16x8 b, f32x4 c) {
  return __builtin_amdgcn_mfma_f32_16x16x32_bf16(a, b, c, 0, 0, 0);
}

// async global->LDS, 16B per lane; LDS dest = wave-uniform base + lane*16
__device__ __forceinline__ void gload16(const bf16_t* g, bf16_t* l) {
  __builtin_amdgcn_global_load_lds((const AS_G void*)g, (AS_L void*)l, 16, 0, 0);
}

__global__ void cvt_f32_bf16_k(const float* __restrict__ in, bf16_t* __restrict__ out, int n4) {
  int i = blockIdx.x * blockDim.x + threadIdx.x;
  int stride = gridDim.x * blockDim.x;
  for (; i < n4; i += stride) {
    float4 v = reinterpret_cast<const float4*>(in)[i];
    union { bf16_t b[4]; short4 s; } u;
    u.b[0] = (bf16_t)v.x; u.b[1] = (bf16_t)v.y;
    u.b[2] = (bf16_t)v.z; u.b[3] = (bf16_t)v.w;
    reinterpret_cast<short4*>(out)[i] = u.s;
  }
}

// C = A(M x K, row) * B(N x K, row)^T.  128x128 tile, BK=32, 4 waves (2x2), m97 structure.
// EPI=0: scatter into Q (scaled 0.125), K as [B,H,L,D] bf16; V transposed as [B,H,D,L] bf16.
// EPI=1: plain fp32 row-major output.
template <int EPI>
__global__ __launch_bounds__(256)
void gemm_bt(const bf16_t* __restrict__ A, const bf16_t* __restrict__ Bm,
             bf16_t* __restrict__ q_out, bf16_t* __restrict__ k_out,
             bf16_t* __restrict__ vt_out, float* __restrict__ f_out,
             int M, int N, int K) {
  __shared__ __align__(16) bf16_t lA[128 * 32];
  __shared__ __align__(16) bf16_t lB[128 * 32];
  const int lane = threadIdx.x & 63;
  const int wid = threadIdx.x >> 6;
  const int m0 = blockIdx.y * 128;
  const int n0 = blockIdx.x * 128;
  const int wr = (wid >> 1) * 64;
  const int wc = (wid & 1) * 64;
  const int lr = lane & 15;
  const int lg = lane >> 4;
  const int srow = lane >> 2;        // 16 rows per 1KB segment
  const int scol = (lane & 3) * 8;   // 4 lanes x 8 bf16 per 32-elem row
  const int s0 = wid * 2, s1 = s0 + 1;

  f32x4 acc[4][4] = {};

  for (int k0 = 0; k0 < K; k0 += 32) {
    gload16(A + (size_t)(m0 + s0 * 16 + srow) * K + k0 + scol, &lA[s0 * 512]);
    gload16(A + (size_t)(m0 + s1 * 16 + srow) * K + k0 + scol, &lA[s1 * 512]);
    gload16(Bm + (size_t)(n0 + s0 * 16 + srow) * K + k0 + scol, &lB[s0 * 512]);
    gload16(Bm + (size_t)(n0 + s1 * 16 + srow) * K + k0 + scol, &lB[s1 * 512]);
    __syncthreads();  // drains vmcnt: LDS tile ready
    bf16x8 af[4], bfr[4];
#pragma unroll
    for (int m = 0; m < 4; ++m)
      af[m] = *reinterpret_cast<const bf16x8*>(&lA[(wr + m * 16 + lr) * 32 + lg * 8]);
#pragma unroll
    for (int n = 0; n < 4; ++n)
      bfr[n] = *reinterpret_cast<const bf16x8*>(&lB[(wc + n * 16 + lr) * 32 + lg * 8]);
#pragma unroll
    for (int m = 0; m < 4; ++m)
#pragma unroll
      for (int n = 0; n < 4; ++n)
        acc[m][n] = mfma16(af[m], bfr[n], acc[m][n]);
    __syncthreads();  // all reads done before next stage overwrites
  }

  if (EPI == 0) {
#pragma unroll
    for (int n = 0; n < 4; ++n) {
      const int gn = n0 + wc + n * 16 + lr;   // output col = lane&15
      const int sec = gn >> 10;               // 0=q 1=k 2=v
      const int hd = gn & 1023;
      const int h = hd >> 6, d = hd & 63;
#pragma unroll
      for (int m = 0; m < 4; ++m) {
        const int gm0 = m0 + wr + m * 16 + lg * 4;  // rows = (lane>>4)*4 + reg
        if (sec == 0) {
#pragma unroll
          for (int r = 0; r < 4; ++r) {
            const int gm = gm0 + r;
            q_out[((size_t)((gm >> 11) * 16 + h) * 2048 + (gm & 2047)) * 64 + d] =
                (bf16_t)(acc[m][n][r] * 0.125f);  // fold 1/sqrt(64)
          }
        } else if (sec == 1) {
#pragma unroll
          for (int r = 0; r < 4; ++r) {
            const int gm = gm0 + r;
            k_out[((size_t)((gm >> 11) * 16 + h) * 2048 + (gm & 2047)) * 64 + d] =
                (bf16_t)acc[m][n][r];
          }
        } else {
          // V transposed: [B,H,D,L]; 4 fragment regs = 4 consecutive tokens -> 8B store
          union { bf16_t b[4]; short4 s; } u;
#pragma unroll
          for (int r = 0; r < 4; ++r) u.b[r] = (bf16_t)acc[m][n][r];
          const int b = gm0 >> 11, sl = gm0 & 2047;
          *reinterpret_cast<short4*>(
              &vt_out[((size_t)(b * 16 + h) * 64 + d) * 2048 + sl]) = u.s;
        }
      }
    }
  } else {
#pragma unroll
    for (int m = 0; m < 4; ++m) {
      const int gm0 = m0 + wr + m * 16 + lg * 4;
#pragma unroll
      for (int n = 0; n < 4; ++n) {
        const int gn = n0 + wc + n * 16 + lr;
#pragma unroll
        for (int r = 0; r < 4; ++r)
          f_out[(size_t)(gm0 + r) * N + gn] = acc[m][n][r];
      }
    }
  }
}

// Flash attention, causal. Block: 4 waves, 64 q-rows (16 per wave), KVBLK=64.
// Q/K in [B,H,L,D] bf16 (Q pre-scaled), V in [B,H,D,L] bf16.
// S = mfma(Q-as-A, K-loaded-A-style-as-B) = Q*K^T (A.B^T identity).
// PV: P via per-wave LDS roundtrip (C-layout -> A-layout), V loads already B-layout.
__global__ __launch_bounds__(256)
void attn_fwd(const bf16_t* __restrict__ Q, const bf16_t* __restrict__ Km,
              const bf16_t* __restrict__ Vt, bf16_t* __restrict__ ctx, int L) {
  const int lane = threadIdx.x & 63;
  const int wid = threadIdx.x >> 6;
  const int qt = blockIdx.x;
  const int bh = blockIdx.y;
  const int lr = lane & 15, lg = lane >> 4;
  const int q0 = qt * 64;
  const int qr0 = q0 + wid * 16;
  const bf16_t* Qh = Q + (size_t)bh * L * 64;
  const bf16_t* Kh = Km + (size_t)bh * L * 64;
  const bf16_t* Vh = Vt + (size_t)bh * 64 * L;

  // stride 72 (=144B, 16B-aligned, 36 dwords): breaks the 32-dword-stride bank pathology
  __shared__ __align__(16) bf16_t P_lds[4][16][72];

  bf16x8 aq[2];
#pragma unroll
  for (int c = 0; c < 2; ++c)
    aq[c] = *reinterpret_cast<const bf16x8*>(&Qh[(size_t)(qr0 + lr) * 64 + c * 32 + lg * 8]);

  f32x4 acc_o[4] = {};
  float m_run[4], l_run[4];
#pragma unroll
  for (int r = 0; r < 4; ++r) { m_run[r] = -1e30f; l_run[r] = 0.f; }

  const int ntiles = qt + 1;
  for (int t = 0; t < ntiles; ++t) {
    const int kb0 = t * 64;
    bf16x8 kf[4][2], vf[4][2];
#pragma unroll
    for (int n = 0; n < 4; ++n)
#pragma unroll
      for (int c = 0; c < 2; ++c) {
        kf[n][c] = *reinterpret_cast<const bf16x8*>(
            &Kh[(size_t)(kb0 + n * 16 + lr) * 64 + c * 32 + lg * 8]);
        vf[n][c] = *reinterpret_cast<const bf16x8*>(
            &Vh[(size_t)(n * 16 + lr) * L + kb0 + c * 32 + lg * 8]);
      }
    const f32x4 zero = {0.f, 0.f, 0.f, 0.f};
    f32x4 s[4];
#pragma unroll
    for (int n = 0; n < 4; ++n) {
      s[n] = mfma16(aq[0], kf[n][0], zero);
      s[n] = mfma16(aq[1], kf[n][1], s[n]);
    }
    if (t == qt) {  // diagonal tile: mask k > q
#pragma unroll
      for (int n = 0; n < 4; ++n) {
        const int kg = kb0 + n * 16 + lr;
#pragma unroll
        for (int r = 0; r < 4; ++r)
          if (kg > qr0 + lg * 4 + r) s[n][r] = -1e30f;
      }
    }
    // online softmax; lane's rows q=(lane>>4)*4+r, cols k=(lane&15)+16n
    float tmax[4];
#pragma unroll
    for (int r = 0; r < 4; ++r)
      tmax[r] = fmaxf(fmaxf(s[0][r], s[1][r]), fmaxf(s[2][r], s[3][r]));
#pragma unroll
    for (int msk = 1; msk <= 8; msk <<= 1)
#pragma unroll
      for (int r = 0; r < 4; ++r)
        tmax[r] = fmaxf(tmax[r], __shfl_xor(tmax[r], msk));
    float alpha[4];
#pragma unroll
    for (int r = 0; r < 4; ++r) {
      const float mn = fmaxf(m_run[r], tmax[r]);
      alpha[r] = __expf(m_run[r] - mn);
      m_run[r] = mn;
    }
    float ls[4] = {0.f, 0.f, 0.f, 0.f};
#pragma unroll
    for (int n = 0; n < 4; ++n)
#pragma unroll
      for (int r = 0; r < 4; ++r) {
        const float p = __expf(s[n][r] - m_run[r]);
        s[n][r] = p;
        ls[r] += p;
      }
#pragma unroll
    for (int msk = 1; msk <= 8; msk <<= 1)
#pragma unroll
      for (int r = 0; r < 4; ++r) ls[r] += __shfl_xor(ls[r], msk);
#pragma unroll
    for (int r = 0; r < 4; ++r) l_run[r] = l_run[r] * alpha[r] + ls[r];
#pragma unroll
    for (int n = 0; n < 4; ++n)
#pragma unroll
      for (int r = 0; r < 4; ++r) acc_o[n][r] *= alpha[r];
    // P: C-layout -> per-wave LDS -> A-layout (wave-private region, no barrier)
#pragma unroll
    for (int n = 0; n < 4; ++n)
#pragma unroll
      for (int r = 0; r < 4; ++r)
        P_lds[wid][lg * 4 + r][lr + 16 * n] = (bf16_t)s[n][r];
    bf16x8 pa[2];
#pragma unroll
    for (int c = 0; c < 2; ++c)
      pa[c] = *reinterpret_cast<const bf16x8*>(&P_lds[wid][lr][c * 32 + lg * 8]);
#pragma unroll
    for (int n = 0; n < 4; ++n) {
      acc_o[n] = mfma16(pa[0], vf[n][0], acc_o[n]);
      acc_o[n] = mfma16(pa[1], vf[n][1], acc_o[n]);
    }
  }
  const int b = bh >> 4, h = bh & 15;
#pragma unroll
  for (int r = 0; r < 4; ++r) {
    const float inv = 1.f / l_run[r];
    const size_t row = (size_t)(b * 2048 + qr0 + lg * 4 + r) * 1024 + h * 64;
#pragma unroll
    for (int n = 0; n < 4; ++n)
      ctx[row + n * 16 + lr] = (bf16_t)(acc_o[n][r] * inv);
  }
}

extern "C" void kernel_launch(void* const* d_in, const int* in_sizes, int n_in,
                              void* d_out, int out_size, void* d_ws, size_t ws_size,
                              hipStream_t stream) {
  (void)in_sizes; (void)n_in; (void)out_size; (void)ws_size;
  const float* x     = (const float*)d_in[0];   // [4,2048,1024]
  const float* w_in  = (const float*)d_in[1];   // [3072,1024]
  const float* w_out = (const float*)d_in[2];   // [1024,1024]
  float* out = (float*)d_out;

  char* ws = (char*)d_ws;
  bf16_t* xb   = (bf16_t*)(ws);                         // 8388608 elems
  bf16_t* wib  = (bf16_t*)(ws + 16777216);              // 3145728
  bf16_t* wob  = (bf16_t*)(ws + 23068672);              // 1048576
  bf16_t* Qb   = (bf16_t*)(ws + 25165824);              // [B,H,L,D]
  bf16_t* Kb   = (bf16_t*)(ws + 41943040);              // [B,H,L,D]
  bf16_t* Vtb  = (bf16_t*)(ws + 58720256);              // [B,H,D,L]
  bf16_t* ctxb = (bf16_t*)(ws + 75497472);              // [B,L,C]
  // total ws use: 92,274,688 B

  const int M = 8192, C = 1024, L = 2048;

  {
    int n4 = 8388608 / 4, blk = (n4 + 255) / 256; if (blk > 2048) blk = 2048;
    cvt_f32_bf16_k<<<blk, 256, 0, stream>>>(x, xb, n4);
  }
  {
    int n4 = 3145728 / 4, blk = (n4 + 255) / 256; if (blk > 2048) blk = 2048;
    cvt_f32_bf16_k<<<blk, 256, 0, stream>>>(w_in, wib, n4);
  }
  {
    int n4 = 1048576 / 4, blk = (n4 + 255) / 256; if (blk > 2048) blk = 2048;
    cvt_f32_bf16_k<<<blk, 256, 0, stream>>>(w_out, wob, n4);
  }

  gemm_bt<0><<<dim3(3072 / 128, M / 128), 256, 0, stream>>>(
      xb, wib, Qb, Kb, Vtb, nullptr, M, 3072, C);

  attn_fwd<<<dim3(L / 64, 64), 256, 0, stream>>>(Qb, Kb, Vtb, ctxb, L);

  gemm_bt<1><<<dim3(C / 128, M / 128), 256, 0, stream>>>(
      ctxb, wob, nullptr, nullptr, nullptr, out, M, C, C);
}

// Round 4
// 342.067 us; speedup vs baseline: 1.8896x; 1.8896x over previous
//
#include <hip/hip_runtime.h>
#include <math.h>

typedef __bf16 bf16_t;
typedef __attribute__((ext_vector_type(8))) __bf16 bf16x8;
typedef __attribute__((ext_vector_type(4))) float f32x4;

#define AS_G __attribute__((address_space(1)))
#define AS_L __attribute__((address_space(3)))

__device__ __forceinline__ f32x4 mfma16(bf16x8 a, bf16x8 b, f32x4 c) {
  return __builtin_amdgcn_mfma_f32_16x16x32_bf16(a, b, c, 0, 0, 0);
}

// async global->LDS, 16B per lane; LDS dest = wave-uniform base + lane*16
__device__ __forceinline__ void gload16(const bf16_t* g, bf16_t* l) {
  __builtin_amdgcn_global_load_lds((const AS_G void*)g, (AS_L void*)l, 16, 0, 0);
}

__global__ void cvt_f32_bf16_k(const float* __restrict__ in, bf16_t* __restrict__ out, int n4) {
  int i = blockIdx.x * blockDim.x + threadIdx.x;
  int stride = gridDim.x * blockDim.x;
  for (; i < n4; i += stride) {
    float4 v = reinterpret_cast<const float4*>(in)[i];
    union { bf16_t b[4]; short4 s; } u;
    u.b[0] = (bf16_t)v.x; u.b[1] = (bf16_t)v.y;
    u.b[2] = (bf16_t)v.z; u.b[3] = (bf16_t)v.w;
    reinterpret_cast<short4*>(out)[i] = u.s;
  }
}

// C = A(M x K, row) * B(N x K, row)^T.  128x128 tile, BK=32, 4 waves (2x2), m97 structure.
// EPI=0: scatter into Q (scaled 0.125), K as [B,H,L,D] bf16; V transposed as [B,H,D,L] bf16.
// EPI=1: plain fp32 row-major output.
template <int EPI>
__global__ __launch_bounds__(256)
void gemm_bt(const bf16_t* __restrict__ A, const bf16_t* __restrict__ Bm,
             bf16_t* __restrict__ q_out, bf16_t* __restrict__ k_out,
             bf16_t* __restrict__ vt_out, float* __restrict__ f_out,
             int M, int N, int K) {
  __shared__ __align__(16) bf16_t lA[128 * 32];
  __shared__ __align__(16) bf16_t lB[128 * 32];
  const int lane = threadIdx.x & 63;
  const int wid = threadIdx.x >> 6;
  const int m0 = blockIdx.y * 128;
  const int n0 = blockIdx.x * 128;
  const int wr = (wid >> 1) * 64;
  const int wc = (wid & 1) * 64;
  const int lr = lane & 15;
  const int lg = lane >> 4;
  const int srow = lane >> 2;        // 16 rows per 1KB segment
  const int scol = (lane & 3) * 8;   // 4 lanes x 8 bf16 per 32-elem row
  const int s0 = wid * 2, s1 = s0 + 1;

  f32x4 acc[4][4] = {};

  for (int k0 = 0; k0 < K; k0 += 32) {
    gload16(A + (size_t)(m0 + s0 * 16 + srow) * K + k0 + scol, &lA[s0 * 512]);
    gload16(A + (size_t)(m0 + s1 * 16 + srow) * K + k0 + scol, &lA[s1 * 512]);
    gload16(Bm + (size_t)(n0 + s0 * 16 + srow) * K + k0 + scol, &lB[s0 * 512]);
    gload16(Bm + (size_t)(n0 + s1 * 16 + srow) * K + k0 + scol, &lB[s1 * 512]);
    __syncthreads();  // drains vmcnt: LDS tile ready
    bf16x8 af[4], bfr[4];
#pragma unroll
    for (int m = 0; m < 4; ++m)
      af[m] = *reinterpret_cast<const bf16x8*>(&lA[(wr + m * 16 + lr) * 32 + lg * 8]);
#pragma unroll
    for (int n = 0; n < 4; ++n)
      bfr[n] = *reinterpret_cast<const bf16x8*>(&lB[(wc + n * 16 + lr) * 32 + lg * 8]);
#pragma unroll
    for (int m = 0; m < 4; ++m)
#pragma unroll
      for (int n = 0; n < 4; ++n)
        acc[m][n] = mfma16(af[m], bfr[n], acc[m][n]);
    __syncthreads();  // all reads done before next stage overwrites
  }

  if (EPI == 0) {
#pragma unroll
    for (int n = 0; n < 4; ++n) {
      const int gn = n0 + wc + n * 16 + lr;   // output col = lane&15
      const int sec = gn >> 10;               // 0=q 1=k 2=v
      const int hd = gn & 1023;
      const int h = hd >> 6, d = hd & 63;
#pragma unroll
      for (int m = 0; m < 4; ++m) {
        const int gm0 = m0 + wr + m * 16 + lg * 4;  // rows = (lane>>4)*4 + reg
        if (sec == 0) {
#pragma unroll
          for (int r = 0; r < 4; ++r) {
            const int gm = gm0 + r;
            q_out[((size_t)((gm >> 11) * 16 + h) * 2048 + (gm & 2047)) * 64 + d] =
                (bf16_t)(acc[m][n][r] * 0.125f);  // fold 1/sqrt(64)
          }
        } else if (sec == 1) {
#pragma unroll
          for (int r = 0; r < 4; ++r) {
            const int gm = gm0 + r;
            k_out[((size_t)((gm >> 11) * 16 + h) * 2048 + (gm & 2047)) * 64 + d] =
                (bf16_t)acc[m][n][r];
          }
        } else {
          // V transposed: [B,H,D,L]; 4 fragment regs = 4 consecutive tokens -> 8B store
          union { bf16_t b[4]; short4 s; } u;
#pragma unroll
          for (int r = 0; r < 4; ++r) u.b[r] = (bf16_t)acc[m][n][r];
          const int b = gm0 >> 11, sl = gm0 & 2047;
          *reinterpret_cast<short4*>(
              &vt_out[((size_t)(b * 16 + h) * 64 + d) * 2048 + sl]) = u.s;
        }
      }
    }
  } else {
#pragma unroll
    for (int m = 0; m < 4; ++m) {
      const int gm0 = m0 + wr + m * 16 + lg * 4;
#pragma unroll
      for (int n = 0; n < 4; ++n) {
        const int gn = n0 + wc + n * 16 + lr;
#pragma unroll
        for (int r = 0; r < 4; ++r)
          f_out[(size_t)(gm0 + r) * N + gn] = acc[m][n][r];
      }
    }
  }
}

// Flash attention, causal. Block: 4 waves, 64 q-rows (16 per wave), KVBLK=64.
// Q/K in [B,H,L,D] bf16 (Q pre-scaled), V in [B,H,D,L] bf16.
// K/V LDS-staged once per block (global_load_lds), double-buffered (T3 2-phase),
// XOR-swizzled layout: chunk c of row r stored at position c^(r&7) (16B chunks).
// Staging uses linear LDS dest + inverse-swizzled GLOBAL source (rule #21).
__global__ __launch_bounds__(256)
void attn_fwd(const bf16_t* __restrict__ Q, const bf16_t* __restrict__ Km,
              const bf16_t* __restrict__ Vt, bf16_t* __restrict__ ctx, int L) {
  __shared__ __align__(16) bf16_t lK[2][64 * 64];
  __shared__ __align__(16) bf16_t lV[2][64 * 64];
  // stride 72 elems: P roundtrip bank-conflict-free-ish (verified: read is 8x8 optimal)
  __shared__ __align__(16) bf16_t P_lds[4][16][72];

  const int lane = threadIdx.x & 63;
  const int wid = threadIdx.x >> 6;
  // bijective XCD swizzle (2048 blocks, 8 XCDs): each XCD gets 8 contiguous heads
  // = 4MB of K/V -> L2-resident. Long tiles first for makespan.
  const int nid = (blockIdx.x & 7) * 256 + (blockIdx.x >> 3);
  const int bh = nid >> 5;
  const int qt = 31 - (nid & 31);
  const int lr = lane & 15, lg = lane >> 4;
  const int qr0 = qt * 64 + wid * 16;
  const bf16_t* Qh = Q + (size_t)bh * L * 64;
  const bf16_t* Kh = Km + (size_t)bh * L * 64;
  const bf16_t* Vh = Vt + (size_t)bh * 64 * L;

  bf16x8 aq[2];
#pragma unroll
  for (int c = 0; c < 2; ++c)
    aq[c] = *reinterpret_cast<const bf16x8*>(&Qh[(size_t)(qr0 + lr) * 64 + c * 32 + lg * 8]);

  f32x4 acc_o[4] = {};
  float m_run[4], l_run[4];
#pragma unroll
  for (int r = 0; r < 4; ++r) { m_run[r] = -1e30f; l_run[r] = 0.f; }

  const int ntiles = qt + 1;
  // staging decomposition: 8 groups of 8 rows per tile; wave stages groups wid*2, wid*2+1
  const int row8 = lane >> 3;            // row within 8-row group
  const int csrc8 = ((lane & 7) ^ row8) * 8;  // inverse-swizzled source chunk (elems)

  // prologue: stage tile 0 into buf 0
#pragma unroll
  for (int g = 0; g < 2; ++g) {
    const int grp = wid * 2 + g;
    const int r = grp * 8 + row8;
    gload16(Kh + (size_t)r * 64 + csrc8, &lK[0][grp * 512]);
    gload16(Vh + (size_t)r * L + csrc8, &lV[0][grp * 512]);
  }

  int cur = 0;
  for (int t = 0; t < ntiles; ++t) {
    __syncthreads();  // implicit vmcnt(0): buf[cur] staged; prev iter's reads of buf[cur^1] done
    if (t + 1 < ntiles) {
      const int knext = (t + 1) * 64;
#pragma unroll
      for (int g = 0; g < 2; ++g) {
        const int grp = wid * 2 + g;
        const int r = grp * 8 + row8;
        gload16(Kh + (size_t)(knext + r) * 64 + csrc8, &lK[cur ^ 1][grp * 512]);
        gload16(Vh + (size_t)r * L + knext + csrc8, &lV[cur ^ 1][grp * 512]);
      }
    }
    const bf16_t* tK = lK[cur];
    const bf16_t* tV = lV[cur];
    const int kb0 = t * 64;
    const int sw0 = (lg ^ (lr & 7)) * 8;        // swizzled pos, chunk lg (c=0)
    const int sw1 = ((4 + lg) ^ (lr & 7)) * 8;  // swizzled pos, chunk 4+lg (c=1)

    const f32x4 zero = {0.f, 0.f, 0.f, 0.f};
    f32x4 s[4];
#pragma unroll
    for (int n = 0; n < 4; ++n) {
      bf16x8 k0 = *reinterpret_cast<const bf16x8*>(&tK[(n * 16 + lr) * 64 + sw0]);
      bf16x8 k1 = *reinterpret_cast<const bf16x8*>(&tK[(n * 16 + lr) * 64 + sw1]);
      s[n] = mfma16(aq[0], k0, zero);
      s[n] = mfma16(aq[1], k1, s[n]);
    }
    if (t == ntiles - 1) {  // diagonal tile: mask k > q
#pragma unroll
      for (int n = 0; n < 4; ++n) {
        const int kg = kb0 + n * 16 + lr;
#pragma unroll
        for (int r = 0; r < 4; ++r)
          if (kg > qr0 + lg * 4 + r) s[n][r] = -1e30f;
      }
    }
    // online softmax; lane's rows q=(lane>>4)*4+r, cols k=(lane&15)+16n
    float tmax[4];
#pragma unroll
    for (int r = 0; r < 4; ++r)
      tmax[r] = fmaxf(fmaxf(s[0][r], s[1][r]), fmaxf(s[2][r], s[3][r]));
#pragma unroll
    for (int msk = 1; msk <= 8; msk <<= 1)
#pragma unroll
      for (int r = 0; r < 4; ++r)
        tmax[r] = fmaxf(tmax[r], __shfl_xor(tmax[r], msk));
    float alpha[4];
#pragma unroll
    for (int r = 0; r < 4; ++r) {
      const float mn = fmaxf(m_run[r], tmax[r]);
      alpha[r] = __expf(m_run[r] - mn);
      m_run[r] = mn;
    }
    float ls[4] = {0.f, 0.f, 0.f, 0.f};
#pragma unroll
    for (int n = 0; n < 4; ++n)
#pragma unroll
      for (int r = 0; r < 4; ++r) {
        const float p = __expf(s[n][r] - m_run[r]);
        s[n][r] = p;
        ls[r] += p;
      }
#pragma unroll
    for (int msk = 1; msk <= 8; msk <<= 1)
#pragma unroll
      for (int r = 0; r < 4; ++r) ls[r] += __shfl_xor(ls[r], msk);
#pragma unroll
    for (int r = 0; r < 4; ++r) l_run[r] = l_run[r] * alpha[r] + ls[r];
#pragma unroll
    for (int n = 0; n < 4; ++n)
#pragma unroll
      for (int r = 0; r < 4; ++r) acc_o[n][r] *= alpha[r];
    // P: C-layout -> per-wave LDS -> A-layout (wave-private region, no barrier)
#pragma unroll
    for (int n = 0; n < 4; ++n)
#pragma unroll
      for (int r = 0; r < 4; ++r)
        P_lds[wid][lg * 4 + r][lr + 16 * n] = (bf16_t)s[n][r];
    bf16x8 pa[2];
#pragma unroll
    for (int c = 0; c < 2; ++c)
      pa[c] = *reinterpret_cast<const bf16x8*>(&P_lds[wid][lr][c * 32 + lg * 8]);
#pragma unroll
    for (int n = 0; n < 4; ++n) {
      bf16x8 v0 = *reinterpret_cast<const bf16x8*>(&tV[(n * 16 + lr) * 64 + sw0]);
      bf16x8 v1 = *reinterpret_cast<const bf16x8*>(&tV[(n * 16 + lr) * 64 + sw1]);
      acc_o[n] = mfma16(pa[0], v0, acc_o[n]);
      acc_o[n] = mfma16(pa[1], v1, acc_o[n]);
    }
    cur ^= 1;
  }
  const int b = bh >> 4, h = bh & 15;
#pragma unroll
  for (int r = 0; r < 4; ++r) {
    const float inv = 1.f / l_run[r];
    const size_t row = (size_t)(b * 2048 + qr0 + lg * 4 + r) * 1024 + h * 64;
#pragma unroll
    for (int n = 0; n < 4; ++n)
      ctx[row + n * 16 + lr] = (bf16_t)(acc_o[n][r] * inv);
  }
}

extern "C" void kernel_launch(void* const* d_in, const int* in_sizes, int n_in,
                              void* d_out, int out_size, void* d_ws, size_t ws_size,
                              hipStream_t stream) {
  (void)in_sizes; (void)n_in; (void)out_size; (void)ws_size;
  const float* x     = (const float*)d_in[0];   // [4,2048,1024]
  const float* w_in  = (const float*)d_in[1];   // [3072,1024]
  const float* w_out = (const float*)d_in[2];   // [1024,1024]
  float* out = (float*)d_out;

  char* ws = (char*)d_ws;
  bf16_t* xb   = (bf16_t*)(ws);                         // 8388608 elems
  bf16_t* wib  = (bf16_t*)(ws + 16777216);              // 3145728
  bf16_t* wob  = (bf16_t*)(ws + 23068672);              // 1048576
  bf16_t* Qb   = (bf16_t*)(ws + 25165824);              // [B,H,L,D]
  bf16_t* Kb   = (bf16_t*)(ws + 41943040);              // [B,H,L,D]
  bf16_t* Vtb  = (bf16_t*)(ws + 58720256);              // [B,H,D,L]
  bf16_t* ctxb = (bf16_t*)(ws + 75497472);              // [B,L,C]
  // total ws use: 92,274,688 B

  const int M = 8192, C = 1024, L = 2048;

  {
    int n4 = 8388608 / 4, blk = (n4 + 255) / 256; if (blk > 2048) blk = 2048;
    cvt_f32_bf16_k<<<blk, 256, 0, stream>>>(x, xb, n4);
  }
  {
    int n4 = 3145728 / 4, blk = (n4 + 255) / 256; if (blk > 2048) blk = 2048;
    cvt_f32_bf16_k<<<blk, 256, 0, stream>>>(w_in, wib, n4);
  }
  {
    int n4 = 1048576 / 4, blk = (n4 + 255) / 256; if (blk > 2048) blk = 2048;
    cvt_f32_bf16_k<<<blk, 256, 0, stream>>>(w_out, wob, n4);
  }

  gemm_bt<0><<<dim3(3072 / 128, M / 128), 256, 0, stream>>>(
      xb, wib, Qb, Kb, Vtb, nullptr, M, 3072, C);

  attn_fwd<<<2048, 256, 0, stream>>>(Qb, Kb, Vtb, ctxb, L);

  gemm_bt<1><<<dim3(C / 128, M / 128), 256, 0, stream>>>(
      ctxb, wob, nullptr, nullptr, nullptr, out, M, C, C);
}

// Round 6
// 304.973 us; speedup vs baseline: 2.1194x; 1.1216x over previous
//
#include <hip/hip_runtime.h>
#include <math.h>

typedef __bf16 bf16_t;
typedef __attribute__((ext_vector_type(8))) __bf16 bf16x8;
typedef __attribute__((ext_vector_type(4))) float f32x4;
typedef __attribute__((ext_vector_type(16))) float f32x16;

#define AS_G __attribute__((address_space(1)))
#define AS_L __attribute__((address_space(3)))

__device__ __forceinline__ f32x4 mfma16(bf16x8 a, bf16x8 b, f32x4 c) {
  return __builtin_amdgcn_mfma_f32_16x16x32_bf16(a, b, c, 0, 0, 0);
}
__device__ __forceinline__ f32x16 mfma32(bf16x8 a, bf16x8 b, f32x16 c) {
  return __builtin_amdgcn_mfma_f32_32x32x16_bf16(a, b, c, 0, 0, 0);
}

// async global->LDS, 16B per lane; LDS dest = wave-uniform base + lane*16
__device__ __forceinline__ void gload16(const bf16_t* g, bf16_t* l) {
  __builtin_amdgcn_global_load_lds((const AS_G void*)g, (AS_L void*)l, 16, 0, 0);
}

__global__ void cvt_f32_bf16_k(const float* __restrict__ in, bf16_t* __restrict__ out, int n4) {
  int i = blockIdx.x * blockDim.x + threadIdx.x;
  int stride = gridDim.x * blockDim.x;
  for (; i < n4; i += stride) {
    float4 v = reinterpret_cast<const float4*>(in)[i];
    union { bf16_t b[4]; short4 s; } u;
    u.b[0] = (bf16_t)v.x; u.b[1] = (bf16_t)v.y;
    u.b[2] = (bf16_t)v.z; u.b[3] = (bf16_t)v.w;
    reinterpret_cast<short4*>(out)[i] = u.s;
  }
}

// C = A(M x K, row) * B(N x K, row)^T.  128x128 tile, BK=32, 4 waves (2x2), m97 structure.
// EPI=0: scatter into Q (scaled 0.125), K as [B,H,L,D] bf16; V transposed as [B,H,D,L] bf16.
// EPI=1: plain fp32 row-major output.  (verified round 1/4 — unchanged)
template <int EPI>
__global__ __launch_bounds__(256)
void gemm_bt(const bf16_t* __restrict__ A, const bf16_t* __restrict__ Bm,
             bf16_t* __restrict__ q_out, bf16_t* __restrict__ k_out,
             bf16_t* __restrict__ vt_out, float* __restrict__ f_out,
             int M, int N, int K) {
  __shared__ __align__(16) bf16_t lA[128 * 32];
  __shared__ __align__(16) bf16_t lB[128 * 32];
  const int lane = threadIdx.x & 63;
  const int wid = threadIdx.x >> 6;
  const int m0 = blockIdx.y * 128;
  const int n0 = blockIdx.x * 128;
  const int wr = (wid >> 1) * 64;
  const int wc = (wid & 1) * 64;
  const int lr = lane & 15;
  const int lg = lane >> 4;
  const int srow = lane >> 2;
  const int scol = (lane & 3) * 8;
  const int s0 = wid * 2, s1 = s0 + 1;

  f32x4 acc[4][4] = {};

  for (int k0 = 0; k0 < K; k0 += 32) {
    gload16(A + (size_t)(m0 + s0 * 16 + srow) * K + k0 + scol, &lA[s0 * 512]);
    gload16(A + (size_t)(m0 + s1 * 16 + srow) * K + k0 + scol, &lA[s1 * 512]);
    gload16(Bm + (size_t)(n0 + s0 * 16 + srow) * K + k0 + scol, &lB[s0 * 512]);
    gload16(Bm + (size_t)(n0 + s1 * 16 + srow) * K + k0 + scol, &lB[s1 * 512]);
    __syncthreads();
    bf16x8 af[4], bfr[4];
#pragma unroll
    for (int m = 0; m < 4; ++m)
      af[m] = *reinterpret_cast<const bf16x8*>(&lA[(wr + m * 16 + lr) * 32 + lg * 8]);
#pragma unroll
    for (int n = 0; n < 4; ++n)
      bfr[n] = *reinterpret_cast<const bf16x8*>(&lB[(wc + n * 16 + lr) * 32 + lg * 8]);
#pragma unroll
    for (int m = 0; m < 4; ++m)
#pragma unroll
      for (int n = 0; n < 4; ++n)
        acc[m][n] = mfma16(af[m], bfr[n], acc[m][n]);
    __syncthreads();
  }

  if (EPI == 0) {
#pragma unroll
    for (int n = 0; n < 4; ++n) {
      const int gn = n0 + wc + n * 16 + lr;
      const int sec = gn >> 10;
      const int hd = gn & 1023;
      const int h = hd >> 6, d = hd & 63;
#pragma unroll
      for (int m = 0; m < 4; ++m) {
        const int gm0 = m0 + wr + m * 16 + lg * 4;
        if (sec == 0) {
#pragma unroll
          for (int r = 0; r < 4; ++r) {
            const int gm = gm0 + r;
            q_out[((size_t)((gm >> 11) * 16 + h) * 2048 + (gm & 2047)) * 64 + d] =
                (bf16_t)(acc[m][n][r] * 0.125f);
          }
        } else if (sec == 1) {
#pragma unroll
          for (int r = 0; r < 4; ++r) {
            const int gm = gm0 + r;
            k_out[((size_t)((gm >> 11) * 16 + h) * 2048 + (gm & 2047)) * 64 + d] =
                (bf16_t)acc[m][n][r];
          }
        } else {
          union { bf16_t b[4]; short4 s; } u;
#pragma unroll
          for (int r = 0; r < 4; ++r) u.b[r] = (bf16_t)acc[m][n][r];
          const int b = gm0 >> 11, sl = gm0 & 2047;
          *reinterpret_cast<short4*>(
              &vt_out[((size_t)(b * 16 + h) * 64 + d) * 2048 + sl]) = u.s;
        }
      }
    }
  } else {
#pragma unroll
    for (int m = 0; m < 4; ++m) {
      const int gm0 = m0 + wr + m * 16 + lg * 4;
#pragma unroll
      for (int n = 0; n < 4; ++n) {
        const int gn = n0 + wc + n * 16 + lr;
#pragma unroll
        for (int r = 0; r < 4; ++r)
          f_out[(size_t)(gm0 + r) * N + gn] = acc[m][n][r];
      }
    }
  }
}

// Flash attention, causal, swapped-operand 32x32x16 structure (T12 family).
// Block: 4 waves x 32 q-rows = 128 q-rows; KVBLK=64; K/V LDS dbuf via global_load_lds,
// XOR-swizzled (chunk' = chunk ^ (row&7), inverse-swizzle on global source).
// S^T = mfma(A=K-rows, B=Q): lane owns q=lane&31, holds S[q][k=32n+crow(r,hi)],
//   crow(r,hi) = (r&3)+4*hi+8*(r>>2). Row stats fully in-register: 31 VALU + 1 shfl_xor(32).
// PV: O^T = mfma(A=Vt-rows, B=P): output col=lane&31=q -> alpha/l stay lane-local.
// P redistribution (C-layout -> B-frag k-major): 16 packs + 8 shfl_xor(32) + half-selects.
// Defer-max (T13, THR=8): rescale only when __any(pmax > m+8).
__global__ __launch_bounds__(256)
void attn_fwd(const bf16_t* __restrict__ Q, const bf16_t* __restrict__ Km,
              const bf16_t* __restrict__ Vt, bf16_t* __restrict__ ctx, int L) {
  __shared__ __align__(16) bf16_t lK[2][64 * 64];
  __shared__ __align__(16) bf16_t lV[2][64 * 64];

  const int lane = threadIdx.x & 63;
  const int wid = threadIdx.x >> 6;
  // bijective XCD swizzle (1024 blocks): XCD x gets bh in [x*8, x*8+8) = 4MB K/V (L2-fit).
  // qt descending within each head for makespan.
  const int nid = (blockIdx.x & 7) * 128 + (blockIdx.x >> 3);
  const int bh = nid >> 4;
  const int qt = 15 - (nid & 15);
  const int q32 = lane & 31;
  const int hi = lane >> 5;
  const int q0w = qt * 128 + wid * 32;   // wave's first q-row (head-local)
  const int qrow = q0w + q32;            // lane's q-row
  const bf16_t* Qh = Q + (size_t)bh * L * 64;
  const bf16_t* Kh = Km + (size_t)bh * L * 64;
  const bf16_t* Vh = Vt + (size_t)bh * 64 * L;

  // Q B-fragments: bq[c] = Q[qrow][c*16 + hi*8 + j], j=0..7 (B^T[n=q][k=d] layout)
  bf16x8 bq[4];
#pragma unroll
  for (int c = 0; c < 4; ++c)
    bq[c] = *reinterpret_cast<const bf16x8*>(&Qh[(size_t)qrow * 64 + c * 16 + hi * 8]);

  f32x16 oacc[2] = {};           // O[q][d = 32*ms + crow(r,hi)]
  float m_run = -1e30f, l_run = 0.f;

  // staging: 512 chunks(16B) per 64x64 tile; wave stages rows sr0 and sr0+32
  const int sr0 = wid * 8 + (lane >> 3);
  const int sc = ((lane & 7) ^ (sr0 & 7)) * 8;  // inverse-swizzled src col (elems)
  const int nt = 2 * qt + 2;

#define STAGE(buf, kb)                                                      \
  do {                                                                      \
    gload16(Kh + (size_t)((kb) + sr0) * 64 + sc, &lK[buf][wid * 512]);      \
    gload16(Kh + (size_t)((kb) + sr0 + 32) * 64 + sc,                       \
            &lK[buf][2048 + wid * 512]);                                    \
    gload16(Vh + (size_t)sr0 * L + (kb) + sc, &lV[buf][wid * 512]);         \
    gload16(Vh + (size_t)(sr0 + 32) * L + (kb) + sc,                        \
            &lV[buf][2048 + wid * 512]);                                    \
  } while (0)

  STAGE(0, 0);
  int cur = 0;
  for (int t = 0; t < nt; ++t) {
    __syncthreads();  // implicit vmcnt(0): buf[cur] ready; prev reads of buf[cur^1] done
    if (t + 1 < nt) STAGE(cur ^ 1, (t + 1) * 64);
    const int kb = t * 64;
    if (kb <= q0w + 31) {  // wave has unmasked work in this k-tile
      const bf16_t* tK = lK[cur];
      const bf16_t* tV = lV[cur];
      // ---- S^T = K . Q^T ----
      f32x16 sacc[2] = {};
#pragma unroll
      for (int n = 0; n < 2; ++n) {
        const int row = n * 32 + q32;
        const int rx = row & 7;
#pragma unroll
        for (int c = 0; c < 4; ++c) {
          bf16x8 ak = *reinterpret_cast<const bf16x8*>(
              &tK[row * 64 + ((2 * c + hi) ^ rx) * 8]);
          sacc[n] = mfma32(ak, bq[c], sacc[n]);
        }
      }
      // ---- causal mask (diagonal-region tiles only) ----
      if (kb + 63 > q0w) {
#pragma unroll
        for (int n = 0; n < 2; ++n)
#pragma unroll
          for (int r = 0; r < 16; ++r) {
            const int kg = kb + n * 32 + (r & 3) + 4 * hi + 8 * (r >> 2);
            if (kg > qrow) sacc[n][r] = -1e30f;
          }
      }
      // ---- row max: in-lane tree + 1 cross-half shuffle ----
      float v8[8];
#pragma unroll
      for (int i = 0; i < 8; ++i)
        v8[i] = fmaxf(fmaxf(sacc[0][i], sacc[0][i + 8]),
                      fmaxf(sacc[1][i], sacc[1][i + 8]));
      float v4a = fmaxf(v8[0], v8[4]), v4b = fmaxf(v8[1], v8[5]);
      float v4c = fmaxf(v8[2], v8[6]), v4d = fmaxf(v8[3], v8[7]);
      float pm = fmaxf(fmaxf(v4a, v4b), fmaxf(v4c, v4d));
      pm = fmaxf(pm, __shfl_xor(pm, 32));
      // ---- defer-max rescale (T13) ----
      if (__any(pm > m_run + 8.f)) {
        const float mn = fmaxf(m_run, pm);
        const float al = __expf(m_run - mn);
#pragma unroll
        for (int ms = 0; ms < 2; ++ms)
#pragma unroll
          for (int r = 0; r < 16; ++r) oacc[ms][r] *= al;
        l_run *= al;
        m_run = mn;
      }
      // ---- exp + row sum ----
      float ls = 0.f;
#pragma unroll
      for (int n = 0; n < 2; ++n)
#pragma unroll
        for (int r = 0; r < 16; ++r) {
          const float p = __expf(sacc[n][r] - m_run);
          sacc[n][r] = p;
          ls += p;
        }
      ls += __shfl_xor(ls, 32);
      l_run += ls;
      // ---- pack P to bf16 + redistribute to B-frag k-major layout ----
      // lane holds P[q][32n + crow(r,hi)]; B-frag needs P[q][16*s4 + hi*8 + j].
      // w[j] = pack(p[2j], p[2j+1]); partner half via shfl_xor(32); select by hi.
      bf16x8 pb[4];
#pragma unroll
      for (int n = 0; n < 2; ++n) {
        int w[8], pw[8];
#pragma unroll
        for (int j = 0; j < 8; ++j) {
          union { bf16_t b[2]; int i; } u;
          u.b[0] = (bf16_t)sacc[n][2 * j];
          u.b[1] = (bf16_t)sacc[n][2 * j + 1];
          w[j] = u.i;
        }
#pragma unroll
        for (int j = 0; j < 8; ++j) pw[j] = __shfl_xor(w[j], 32);
#pragma unroll
        for (int s = 0; s < 2; ++s) {
          union { int i[4]; bf16x8 v; } pv;
          if (hi == 0) {
            pv.i[0] = w[4 * s];     pv.i[1] = w[4 * s + 1];
            pv.i[2] = pw[4 * s];    pv.i[3] = pw[4 * s + 1];
          } else {
            pv.i[0] = pw[4 * s + 2]; pv.i[1] = pw[4 * s + 3];
            pv.i[2] = w[4 * s + 2];  pv.i[3] = w[4 * s + 3];
          }
          pb[2 * n + s] = pv.v;
        }
      }
      // ---- PV: O^T += Vt . P^T ----
#pragma unroll
      for (int s4 = 0; s4 < 4; ++s4) {
#pragma unroll
        for (int ms = 0; ms < 2; ++ms) {
          const int row = ms * 32 + q32;
          bf16x8 av = *reinterpret_cast<const bf16x8*>(
              &tV[row * 64 + ((2 * s4 + hi) ^ (row & 7)) * 8]);
          oacc[ms] = mfma32(av, pb[s4], oacc[ms]);
        }
      }
    }
    cur ^= 1;
  }
#undef STAGE
  // ---- epilogue: O[q][d]/l, d = 32*ms + 8*rg + 4*hi + i, lane-local l ----
  const float inv = 1.f / l_run;
  const int b = bh >> 4, h = bh & 15;
  const size_t orow = (size_t)(b * 2048 + qrow) * 1024 + h * 64;
#pragma unroll
  for (int ms = 0; ms < 2; ++ms)
#pragma unroll
    for (int rg = 0; rg < 4; ++rg) {
      union { bf16_t b4[4]; short4 s; } u;
#pragma unroll
      for (int i = 0; i < 4; ++i) u.b4[i] = (bf16_t)(oacc[ms][rg * 4 + i] * inv);
      *reinterpret_cast<short4*>(&ctx[orow + ms * 32 + rg * 8 + hi * 4]) = u.s;
    }
}

extern "C" void kernel_launch(void* const* d_in, const int* in_sizes, int n_in,
                              void* d_out, int out_size, void* d_ws, size_t ws_size,
                              hipStream_t stream) {
  (void)in_sizes; (void)n_in; (void)out_size; (void)ws_size;
  const float* x     = (const float*)d_in[0];   // [4,2048,1024]
  const float* w_in  = (const float*)d_in[1];   // [3072,1024]
  const float* w_out = (const float*)d_in[2];   // [1024,1024]
  float* out = (float*)d_out;

  char* ws = (char*)d_ws;
  bf16_t* xb   = (bf16_t*)(ws);                         // 8388608 elems
  bf16_t* wib  = (bf16_t*)(ws + 16777216);              // 3145728
  bf16_t* wob  = (bf16_t*)(ws + 23068672);              // 1048576
  bf16_t* Qb   = (bf16_t*)(ws + 25165824);              // [B,H,L,D]
  bf16_t* Kb   = (bf16_t*)(ws + 41943040);              // [B,H,L,D]
  bf16_t* Vtb  = (bf16_t*)(ws + 58720256);              // [B,H,D,L]
  bf16_t* ctxb = (bf16_t*)(ws + 75497472);              // [B,L,C]

  const int M = 8192, C = 1024, L = 2048;

  {
    int n4 = 8388608 / 4, blk = (n4 + 255) / 256; if (blk > 2048) blk = 2048;
    cvt_f32_bf16_k<<<blk, 256, 0, stream>>>(x, xb, n4);
  }
  {
    int n4 = 3145728 / 4, blk = (n4 + 255) / 256; if (blk > 2048) blk = 2048;
    cvt_f32_bf16_k<<<blk, 256, 0, stream>>>(w_in, wib, n4);
  }
  {
    int n4 = 1048576 / 4, blk = (n4 + 255) / 256; if (blk > 2048) blk = 2048;
    cvt_f32_bf16_k<<<blk, 256, 0, stream>>>(w_out, wob, n4);
  }

  gemm_bt<0><<<dim3(3072 / 128, M / 128), 256, 0, stream>>>(
      xb, wib, Qb, Kb, Vtb, nullptr, M, 3072, C);

  attn_fwd<<<1024, 256, 0, stream>>>(Qb, Kb, Vtb, ctxb, L);

  gemm_bt<1><<<dim3(C / 128, M / 128), 256, 0, stream>>>(
      ctxb, wob, nullptr, nullptr, nullptr, out, M, C, C);
}

// Round 7
// 282.385 us; speedup vs baseline: 2.2889x; 1.0800x over previous
//
#include <hip/hip_runtime.h>
#include <math.h>

typedef __bf16 bf16_t;
typedef __attribute__((ext_vector_type(8))) __bf16 bf16x8;
typedef __attribute__((ext_vector_type(4))) float f32x4;
typedef __attribute__((ext_vector_type(16))) float f32x16;

#define AS_G __attribute__((address_space(1)))
#define AS_L __attribute__((address_space(3)))

__device__ __forceinline__ f32x4 mfma16(bf16x8 a, bf16x8 b, f32x4 c) {
  return __builtin_amdgcn_mfma_f32_16x16x32_bf16(a, b, c, 0, 0, 0);
}
__device__ __forceinline__ f32x16 mfma32(bf16x8 a, bf16x8 b, f32x16 c) {
  return __builtin_amdgcn_mfma_f32_32x32x16_bf16(a, b, c, 0, 0, 0);
}

// async global->LDS, 16B per lane; LDS dest = wave-uniform base + lane*16
__device__ __forceinline__ void gload16(const bf16_t* g, bf16_t* l) {
  __builtin_amdgcn_global_load_lds((const AS_G void*)g, (AS_L void*)l, 16, 0, 0);
}

__global__ void cvt_f32_bf16_k(const float* __restrict__ in, bf16_t* __restrict__ out, int n4) {
  int i = blockIdx.x * blockDim.x + threadIdx.x;
  int stride = gridDim.x * blockDim.x;
  for (; i < n4; i += stride) {
    float4 v = reinterpret_cast<const float4*>(in)[i];
    union { bf16_t b[4]; short4 s; } u;
    u.b[0] = (bf16_t)v.x; u.b[1] = (bf16_t)v.y;
    u.b[2] = (bf16_t)v.z; u.b[3] = (bf16_t)v.w;
    reinterpret_cast<short4*>(out)[i] = u.s;
  }
}

// C = A(M x K, row) * B(N x K, row)^T.  128x128 tile, BK=32, 4 waves (2x2), m97 structure.
// EPI=0: scatter into Q (scaled 0.125), K as [B,H,L,D] bf16; V transposed as [B,H,D,L] bf16.
// EPI=1: plain fp32 row-major output.  (verified rounds 1/4/6 — unchanged)
template <int EPI>
__global__ __launch_bounds__(256)
void gemm_bt(const bf16_t* __restrict__ A, const bf16_t* __restrict__ Bm,
             bf16_t* __restrict__ q_out, bf16_t* __restrict__ k_out,
             bf16_t* __restrict__ vt_out, float* __restrict__ f_out,
             int M, int N, int K) {
  __shared__ __align__(16) bf16_t lA[128 * 32];
  __shared__ __align__(16) bf16_t lB[128 * 32];
  const int lane = threadIdx.x & 63;
  const int wid = threadIdx.x >> 6;
  const int m0 = blockIdx.y * 128;
  const int n0 = blockIdx.x * 128;
  const int wr = (wid >> 1) * 64;
  const int wc = (wid & 1) * 64;
  const int lr = lane & 15;
  const int lg = lane >> 4;
  const int srow = lane >> 2;
  const int scol = (lane & 3) * 8;
  const int s0 = wid * 2, s1 = s0 + 1;

  f32x4 acc[4][4] = {};

  for (int k0 = 0; k0 < K; k0 += 32) {
    gload16(A + (size_t)(m0 + s0 * 16 + srow) * K + k0 + scol, &lA[s0 * 512]);
    gload16(A + (size_t)(m0 + s1 * 16 + srow) * K + k0 + scol, &lA[s1 * 512]);
    gload16(Bm + (size_t)(n0 + s0 * 16 + srow) * K + k0 + scol, &lB[s0 * 512]);
    gload16(Bm + (size_t)(n0 + s1 * 16 + srow) * K + k0 + scol, &lB[s1 * 512]);
    __syncthreads();
    bf16x8 af[4], bfr[4];
#pragma unroll
    for (int m = 0; m < 4; ++m)
      af[m] = *reinterpret_cast<const bf16x8*>(&lA[(wr + m * 16 + lr) * 32 + lg * 8]);
#pragma unroll
    for (int n = 0; n < 4; ++n)
      bfr[n] = *reinterpret_cast<const bf16x8*>(&lB[(wc + n * 16 + lr) * 32 + lg * 8]);
#pragma unroll
    for (int m = 0; m < 4; ++m)
#pragma unroll
      for (int n = 0; n < 4; ++n)
        acc[m][n] = mfma16(af[m], bfr[n], acc[m][n]);
    __syncthreads();
  }

  if (EPI == 0) {
#pragma unroll
    for (int n = 0; n < 4; ++n) {
      const int gn = n0 + wc + n * 16 + lr;
      const int sec = gn >> 10;
      const int hd = gn & 1023;
      const int h = hd >> 6, d = hd & 63;
#pragma unroll
      for (int m = 0; m < 4; ++m) {
        const int gm0 = m0 + wr + m * 16 + lg * 4;
        if (sec == 0) {
#pragma unroll
          for (int r = 0; r < 4; ++r) {
            const int gm = gm0 + r;
            q_out[((size_t)((gm >> 11) * 16 + h) * 2048 + (gm & 2047)) * 64 + d] =
                (bf16_t)(acc[m][n][r] * 0.125f);
          }
        } else if (sec == 1) {
#pragma unroll
          for (int r = 0; r < 4; ++r) {
            const int gm = gm0 + r;
            k_out[((size_t)((gm >> 11) * 16 + h) * 2048 + (gm & 2047)) * 64 + d] =
                (bf16_t)acc[m][n][r];
          }
        } else {
          union { bf16_t b[4]; short4 s; } u;
#pragma unroll
          for (int r = 0; r < 4; ++r) u.b[r] = (bf16_t)acc[m][n][r];
          const int b = gm0 >> 11, sl = gm0 & 2047;
          *reinterpret_cast<short4*>(
              &vt_out[((size_t)(b * 16 + h) * 64 + d) * 2048 + sl]) = u.s;
        }
      }
    }
  } else {
#pragma unroll
    for (int m = 0; m < 4; ++m) {
      const int gm0 = m0 + wr + m * 16 + lg * 4;
#pragma unroll
      for (int n = 0; n < 4; ++n) {
        const int gn = n0 + wc + n * 16 + lr;
#pragma unroll
        for (int r = 0; r < 4; ++r)
          f_out[(size_t)(gm0 + r) * N + gn] = acc[m][n][r];
      }
    }
  }
}

// ---- per-tile attention compute (swapped-operand 32x32x16, verified round 6) ----
// lane owns q = q0w + (lane&31); holds S[q][k=32n+crow(r,hi)], crow=(r&3)+4*hi+8*(r>>2).
__device__ __forceinline__ void attn_tile(
    const bf16_t* __restrict__ tK, const bf16_t* __restrict__ tV,
    int kb, int q0w, int qrow, int q32, int hi,
    const bf16x8 bq[4], f32x16 oacc[2], float& m_run, float& l_run) {
  // ---- S^T = K . Q^T ----
  f32x16 sacc[2] = {};
#pragma unroll
  for (int n = 0; n < 2; ++n) {
    const int row = n * 32 + q32;
    const int rx = row & 7;
#pragma unroll
    for (int c = 0; c < 4; ++c) {
      bf16x8 ak = *reinterpret_cast<const bf16x8*>(
          &tK[row * 64 + ((2 * c + hi) ^ rx) * 8]);
      sacc[n] = mfma32(ak, bq[c], sacc[n]);
    }
  }
  // ---- causal mask (diagonal-region tiles only) ----
  if (kb + 63 > q0w) {
#pragma unroll
    for (int n = 0; n < 2; ++n)
#pragma unroll
      for (int r = 0; r < 16; ++r) {
        const int kg = kb + n * 32 + (r & 3) + 4 * hi + 8 * (r >> 2);
        if (kg > qrow) sacc[n][r] = -1e30f;
      }
  }
  // ---- row max: in-lane tree + 1 cross-half shuffle ----
  float v8[8];
#pragma unroll
  for (int i = 0; i < 8; ++i)
    v8[i] = fmaxf(fmaxf(sacc[0][i], sacc[0][i + 8]),
                  fmaxf(sacc[1][i], sacc[1][i + 8]));
  float pm = fmaxf(fmaxf(fmaxf(v8[0], v8[4]), fmaxf(v8[1], v8[5])),
                   fmaxf(fmaxf(v8[2], v8[6]), fmaxf(v8[3], v8[7])));
  pm = fmaxf(pm, __shfl_xor(pm, 32));
  // ---- defer-max rescale (T13, THR=8) ----
  if (__any(pm > m_run + 8.f)) {
    const float mn = fmaxf(m_run, pm);
    const float al = __expf(m_run - mn);
#pragma unroll
    for (int ms = 0; ms < 2; ++ms)
#pragma unroll
      for (int r = 0; r < 16; ++r) oacc[ms][r] *= al;
    l_run *= al;
    m_run = mn;
  }
  // ---- exp + row sum ----
  float ls = 0.f;
#pragma unroll
  for (int n = 0; n < 2; ++n)
#pragma unroll
    for (int r = 0; r < 16; ++r) {
      const float p = __expf(sacc[n][r] - m_run);
      sacc[n][r] = p;
      ls += p;
    }
  ls += __shfl_xor(ls, 32);
  l_run += ls;
  // ---- pack P to bf16 + redistribute to B-frag k-major layout ----
  bf16x8 pb[4];
#pragma unroll
  for (int n = 0; n < 2; ++n) {
    int w[8], pw[8];
#pragma unroll
    for (int j = 0; j < 8; ++j) {
      union { bf16_t b[2]; int i; } u;
      u.b[0] = (bf16_t)sacc[n][2 * j];
      u.b[1] = (bf16_t)sacc[n][2 * j + 1];
      w[j] = u.i;
    }
#pragma unroll
    for (int j = 0; j < 8; ++j) pw[j] = __shfl_xor(w[j], 32);
#pragma unroll
    for (int s = 0; s < 2; ++s) {
      union { int i[4]; bf16x8 v; } pv;
      if (hi == 0) {
        pv.i[0] = w[4 * s];      pv.i[1] = w[4 * s + 1];
        pv.i[2] = pw[4 * s];     pv.i[3] = pw[4 * s + 1];
      } else {
        pv.i[0] = pw[4 * s + 2]; pv.i[1] = pw[4 * s + 3];
        pv.i[2] = w[4 * s + 2];  pv.i[3] = w[4 * s + 3];
      }
      pb[2 * n + s] = pv.v;
    }
  }
  // ---- PV: O^T += Vt . P^T ----
#pragma unroll
  for (int s4 = 0; s4 < 4; ++s4) {
#pragma unroll
    for (int ms = 0; ms < 2; ++ms) {
      const int row = ms * 32 + q32;
      bf16x8 av = *reinterpret_cast<const bf16x8*>(
          &tV[row * 64 + ((2 * s4 + hi) ^ (row & 7)) * 8]);
      oacc[ms] = mfma32(av, pb[s4], oacc[ms]);
    }
  }
}

__device__ __forceinline__ void attn_epi(bf16_t* __restrict__ ctx, int bh,
                                         int qrow, int hi,
                                         const f32x16 oacc[2], float l_run) {
  const float inv = 1.f / l_run;
  const int b = bh >> 4, h = bh & 15;
  const size_t orow = (size_t)(b * 2048 + qrow) * 1024 + h * 64;
#pragma unroll
  for (int ms = 0; ms < 2; ++ms)
#pragma unroll
    for (int rg = 0; rg < 4; ++rg) {
      union { bf16_t b4[4]; short4 s; } u;
#pragma unroll
      for (int i = 0; i < 4; ++i) u.b4[i] = (bf16_t)(oacc[ms][rg * 4 + i] * inv);
      *reinterpret_cast<short4*>(&ctx[orow + ms * 32 + rg * 8 + hi * 4]) = u.s;
    }
}

// Flash attention, causal — PAIRED q-tiles for perfect load balance.
// 512 blocks = 64 bh x 8 pairs; pair p handles q-tiles jA=15-p (long) and jB=p (short).
// Block stages k-tiles 0..2*jA+1 once; computes A-state on all, B-state while causal.
// Every block: exactly 34 compute-tile visits -> zero tail, 2 blocks/CU sustained.
__global__ __launch_bounds__(256)
void attn_fwd(const bf16_t* __restrict__ Q, const bf16_t* __restrict__ Km,
              const bf16_t* __restrict__ Vt, bf16_t* __restrict__ ctx, int L) {
  __shared__ __align__(16) bf16_t lK[2][64 * 64];
  __shared__ __align__(16) bf16_t lV[2][64 * 64];

  const int lane = threadIdx.x & 63;
  const int wid = threadIdx.x >> 6;
  // XCD swizzle (512 blocks): XCD x gets bh in [x*8, x*8+8) = 4MB K/V (L2-fit).
  const int nid = (blockIdx.x & 7) * 64 + (blockIdx.x >> 3);
  const int bh = nid >> 3;
  const int p = nid & 7;
  const int jA = 15 - p, jB = p;
  const int q32 = lane & 31;
  const int hi = lane >> 5;
  const int q0A = jA * 128 + wid * 32, qrowA = q0A + q32;
  const int q0B = jB * 128 + wid * 32, qrowB = q0B + q32;
  const bf16_t* Qh = Q + (size_t)bh * L * 64;
  const bf16_t* Kh = Km + (size_t)bh * L * 64;
  const bf16_t* Vh = Vt + (size_t)bh * 64 * L;

  // Q B-fragments for both q-tiles: bq[c] = Q[qrow][c*16 + hi*8 + j]
  bf16x8 bqA[4], bqB[4];
#pragma unroll
  for (int c = 0; c < 4; ++c) {
    bqA[c] = *reinterpret_cast<const bf16x8*>(&Qh[(size_t)qrowA * 64 + c * 16 + hi * 8]);
    bqB[c] = *reinterpret_cast<const bf16x8*>(&Qh[(size_t)qrowB * 64 + c * 16 + hi * 8]);
  }

  f32x16 oaccA[2] = {}, oaccB[2] = {};
  float mA = -1e30f, lA_ = 0.f, mB = -1e30f, lB_ = 0.f;

  // staging: 512 chunks(16B) per 64x64 tile; wave stages rows sr0 and sr0+32
  const int sr0 = wid * 8 + (lane >> 3);
  const int sc = ((lane & 7) ^ (sr0 & 7)) * 8;  // inverse-swizzled src col (elems)
  const int nt = 2 * jA + 2;

#define STAGE(buf, kb)                                                      \
  do {                                                                      \
    gload16(Kh + (size_t)((kb) + sr0) * 64 + sc, &lK[buf][wid * 512]);      \
    gload16(Kh + (size_t)((kb) + sr0 + 32) * 64 + sc,                       \
            &lK[buf][2048 + wid * 512]);                                    \
    gload16(Vh + (size_t)sr0 * L + (kb) + sc, &lV[buf][wid * 512]);         \
    gload16(Vh + (size_t)(sr0 + 32) * L + (kb) + sc,                        \
            &lV[buf][2048 + wid * 512]);                                    \
  } while (0)

  STAGE(0, 0);
  int cur = 0;
  for (int t = 0; t < nt; ++t) {
    __syncthreads();  // implicit vmcnt(0): buf[cur] ready; prev reads of buf[cur^1] done
    if (t + 1 < nt) STAGE(cur ^ 1, (t + 1) * 64);
    const int kb = t * 64;
    const bf16_t* tK = lK[cur];
    const bf16_t* tV = lV[cur];
    if (kb <= q0A + 31)
      attn_tile(tK, tV, kb, q0A, qrowA, q32, hi, bqA, oaccA, mA, lA_);
    if (kb <= q0B + 31)
      attn_tile(tK, tV, kb, q0B, qrowB, q32, hi, bqB, oaccB, mB, lB_);
    cur ^= 1;
  }
#undef STAGE
  attn_epi(ctx, bh, qrowA, hi, oaccA, lA_);
  attn_epi(ctx, bh, qrowB, hi, oaccB, lB_);
}

extern "C" void kernel_launch(void* const* d_in, const int* in_sizes, int n_in,
                              void* d_out, int out_size, void* d_ws, size_t ws_size,
                              hipStream_t stream) {
  (void)in_sizes; (void)n_in; (void)out_size; (void)ws_size;
  const float* x     = (const float*)d_in[0];   // [4,2048,1024]
  const float* w_in  = (const float*)d_in[1];   // [3072,1024]
  const float* w_out = (const float*)d_in[2];   // [1024,1024]
  float* out = (float*)d_out;

  char* ws = (char*)d_ws;
  bf16_t* xb   = (bf16_t*)(ws);                         // 8388608 elems
  bf16_t* wib  = (bf16_t*)(ws + 16777216);              // 3145728
  bf16_t* wob  = (bf16_t*)(ws + 23068672);              // 1048576
  bf16_t* Qb   = (bf16_t*)(ws + 25165824);              // [B,H,L,D]
  bf16_t* Kb   = (bf16_t*)(ws + 41943040);              // [B,H,L,D]
  bf16_t* Vtb  = (bf16_t*)(ws + 58720256);              // [B,H,D,L]
  bf16_t* ctxb = (bf16_t*)(ws + 75497472);              // [B,L,C]

  const int M = 8192, C = 1024, L = 2048;

  {
    int n4 = 8388608 / 4, blk = (n4 + 255) / 256; if (blk > 2048) blk = 2048;
    cvt_f32_bf16_k<<<blk, 256, 0, stream>>>(x, xb, n4);
  }
  {
    int n4 = 3145728 / 4, blk = (n4 + 255) / 256; if (blk > 2048) blk = 2048;
    cvt_f32_bf16_k<<<blk, 256, 0, stream>>>(w_in, wib, n4);
  }
  {
    int n4 = 1048576 / 4, blk = (n4 + 255) / 256; if (blk > 2048) blk = 2048;
    cvt_f32_bf16_k<<<blk, 256, 0, stream>>>(w_out, wob, n4);
  }

  gemm_bt<0><<<dim3(3072 / 128, M / 128), 256, 0, stream>>>(
      xb, wib, Qb, Kb, Vtb, nullptr, M, 3072, C);

  attn_fwd<<<512, 256, 0, stream>>>(Qb, Kb, Vtb, ctxb, L);

  gemm_bt<1><<<dim3(C / 128, M / 128), 256, 0, stream>>>(
      ctxb, wob, nullptr, nullptr, nullptr, out, M, C, C);
}